// Round 13
// baseline (423.938 us; speedup 1.0000x reference)
//
#include <hip/hip_runtime.h>

#define HEADS 8
#define FDIM 128          // HEADS*16 = feature width of both conv layers
#define NCLS 16
#define NEG_SLOPE 0.2f
#define LOG2E 1.4426950408889634f

typedef __attribute__((ext_vector_type(8))) short bf16x8;
typedef __attribute__((ext_vector_type(4))) float f32x4;

__device__ __forceinline__ unsigned short f2bf(float f) {
    unsigned u = __float_as_uint(f);
    unsigned r = u + 0x7FFFu + ((u >> 16) & 1u);   // round-to-nearest-even
    return (unsigned short)(r >> 16);
}

// ---------------- fused: dual MFMA-GEMM + padded-CSR build ---------------------
// OPERAND-SWAPPED GEMM: acc = mfma(w_frag, x_frag, acc). Fragment layouts are
// transpose-symmetric, so the LDS W staging and the per-lane X row loads are
// IDENTICAL to the old orientation — but the C/D layout flips: a lane's 4 acc
// registers are 4 CONSECUTIVE COLUMNS of one Y row -> pack into one 8 B store
// (8 stores/thread instead of 32 scalar b16 — R12's hidden VMEM bottleneck).
// Each wave handles TWO 16-row strips (block = 128 rows): every ds_read W-frag
// feeds 2 MFMAs, two independent X-load chains overlap, W staged once/128 rows.
// Roles when SB>0: x%4==3 -> CSR scatter block (interleaved, co-resident).
__global__ __launch_bounds__(256) void gemm_csr(const float* __restrict__ Xf,
                                                const unsigned short* __restrict__ Xb,
                                                const float* __restrict__ W0,
                                                const float* __restrict__ W1,
                                                unsigned short* __restrict__ Y0,
                                                unsigned short* __restrict__ Y1,
                                                int n,
                                                const int* __restrict__ srcs,
                                                const int* __restrict__ dsts,
                                                int* __restrict__ cnt,
                                                int* __restrict__ adj,
                                                int E0, int pad, int GB, int SB) {
    __shared__ __align__(16) unsigned short ws[8 * 4 * 64 * 8];   // 32 KB
    const int t = threadIdx.x;
    const int x = blockIdx.x;
    int gIdx;
    if (SB > 0) {
        if ((x & 3) == 3) {          // scatter role, interleaved
            int i = (x >> 2) * 256 + t;
            const int stride = SB * 256;
            for (; i < E0; i += stride) {
                const int d = dsts[i];
                const int rk = atomicAdd(&cnt[d], 1);
                if (rk < pad) adj[(size_t)d * pad + rk] = srcs[i];
            }
            return;
        }
        gIdx = (x >> 2) * 3 + (x & 3);
    } else {
        gIdx = x;
    }
    if (gIdx >= 2 * GB) return;
    const int side = (gIdx >= GB) ? 1 : 0;
    const float* W = side ? W1 : W0;
    unsigned short* Y = side ? Y1 : Y0;
    const int bid = side ? gIdx - GB : gIdx;

    // ---- stage W (128x128) as bf16 fragments, once per block ----
#pragma unroll
    for (int i = 0; i < 16; i++) {
        const int f = t + i * 256;         // k = f>>5, n4 = f&31
        const int k = f >> 5, n4 = f & 31;
        const float4 v = *(const float4*)(W + k * 128 + n4 * 4);
        const int kc = k >> 5, q = (k >> 3) & 3, j = k & 7;
        const float vv[4] = {v.x, v.y, v.z, v.w};
#pragma unroll
        for (int e = 0; e < 4; e++) {
            const int nn = n4 * 4 + e;
            ws[((((nn >> 4) * 4 + kc) * 64 + q * 16 + (nn & 15)) << 3) + j] = f2bf(vv[e]);
        }
    }
    __syncthreads();

    const int w = t >> 6, lane = t & 63;
    const int q = lane >> 4, jd = lane & 15;
    const bf16x8* wb = (const bf16x8*)ws;

    for (int sb = bid * 128; sb < n; sb += GB * 128) {
        const int row0 = sb + w * 32 + jd;     // strip 0 row owned by this lane
        const int row1 = row0 + 16;            // strip 1 row
        bf16x8 bx0[4], bx1[4];
#pragma unroll
        for (int kc = 0; kc < 4; kc++) {
            bx0[kc] = (bf16x8){0,0,0,0,0,0,0,0};
            bx1[kc] = (bf16x8){0,0,0,0,0,0,0,0};
        }
        if (Xb) {
            if (row0 < n) {
                const unsigned short* xp = Xb + (size_t)row0 * 128 + q * 8;
#pragma unroll
                for (int kc = 0; kc < 4; kc++) bx0[kc] = *(const bf16x8*)(xp + kc * 32);
            }
            if (row1 < n) {
                const unsigned short* xp = Xb + (size_t)row1 * 128 + q * 8;
#pragma unroll
                for (int kc = 0; kc < 4; kc++) bx1[kc] = *(const bf16x8*)(xp + kc * 32);
            }
        } else {
            if (row0 < n) {
                const float* xp = Xf + (size_t)row0 * 128 + q * 8;
#pragma unroll
                for (int kc = 0; kc < 4; kc++) {
                    const float4 v0 = *(const float4*)(xp + kc * 32);
                    const float4 v1 = *(const float4*)(xp + kc * 32 + 4);
                    union { unsigned short us[8]; bf16x8 b; } pk;
                    pk.us[0] = f2bf(v0.x); pk.us[1] = f2bf(v0.y);
                    pk.us[2] = f2bf(v0.z); pk.us[3] = f2bf(v0.w);
                    pk.us[4] = f2bf(v1.x); pk.us[5] = f2bf(v1.y);
                    pk.us[6] = f2bf(v1.z); pk.us[7] = f2bf(v1.w);
                    bx0[kc] = pk.b;
                }
            }
            if (row1 < n) {
                const float* xp = Xf + (size_t)row1 * 128 + q * 8;
#pragma unroll
                for (int kc = 0; kc < 4; kc++) {
                    const float4 v0 = *(const float4*)(xp + kc * 32);
                    const float4 v1 = *(const float4*)(xp + kc * 32 + 4);
                    union { unsigned short us[8]; bf16x8 b; } pk;
                    pk.us[0] = f2bf(v0.x); pk.us[1] = f2bf(v0.y);
                    pk.us[2] = f2bf(v0.z); pk.us[3] = f2bf(v0.w);
                    pk.us[4] = f2bf(v1.x); pk.us[5] = f2bf(v1.y);
                    pk.us[6] = f2bf(v1.z); pk.us[7] = f2bf(v1.w);
                    bx1[kc] = pk.b;
                }
            }
        }
        f32x4 acc0[8], acc1[8];
#pragma unroll
        for (int i = 0; i < 8; i++) {
            acc0[i] = (f32x4){0.f, 0.f, 0.f, 0.f};
            acc1[i] = (f32x4){0.f, 0.f, 0.f, 0.f};
        }
#pragma unroll
        for (int kc = 0; kc < 4; kc++) {
#pragma unroll
            for (int ct = 0; ct < 8; ct++) {
                const bf16x8 aw = wb[(ct * 4 + kc) * 64 + lane];
                acc0[ct] = __builtin_amdgcn_mfma_f32_16x16x32_bf16(aw, bx0[kc], acc0[ct], 0, 0, 0);
                acc1[ct] = __builtin_amdgcn_mfma_f32_16x16x32_bf16(aw, bx1[kc], acc1[ct], 0, 0, 0);
            }
        }
        // epilogue: lane holds 4 consecutive cols (ct*16 + q*4 + r) of its row
        if (row0 < n) {
            unsigned short* yp = Y + (size_t)row0 * 128 + q * 4;
#pragma unroll
            for (int ct = 0; ct < 8; ct++) {
                union { unsigned short us[4]; uint2 u2; } pk;
                pk.us[0] = f2bf(acc0[ct][0]); pk.us[1] = f2bf(acc0[ct][1]);
                pk.us[2] = f2bf(acc0[ct][2]); pk.us[3] = f2bf(acc0[ct][3]);
                *(uint2*)(yp + ct * 16) = pk.u2;
            }
        }
        if (row1 < n) {
            unsigned short* yp = Y + (size_t)row1 * 128 + q * 4;
#pragma unroll
            for (int ct = 0; ct < 8; ct++) {
                union { unsigned short us[4]; uint2 u2; } pk;
                pk.us[0] = f2bf(acc1[ct][0]); pk.us[1] = f2bf(acc1[ct][1]);
                pk.us[2] = f2bf(acc1[ct][2]); pk.us[3] = f2bf(acc1[ct][3]);
                *(uint2*)(yp + ct * 16) = pk.u2;
            }
        }
    }
}

// one edge-step for gather v4 (4 edges/wave, 16-lane groups, 8 ch/lane)
#define GATHER_EDGE4(SRC, GATE)                                              \
    {                                                                        \
        const uint4 lv_ = *(const uint4*)(xl + (size_t)(SRC) * FDIM + col);  \
        const float l0_ = __uint_as_float(lv_.x << 16);                      \
        const float l1_ = __uint_as_float(lv_.x & 0xFFFF0000u);              \
        const float l2_ = __uint_as_float(lv_.y << 16);                      \
        const float l3_ = __uint_as_float(lv_.y & 0xFFFF0000u);              \
        const float l4_ = __uint_as_float(lv_.z << 16);                      \
        const float l5_ = __uint_as_float(lv_.z & 0xFFFF0000u);              \
        const float l6_ = __uint_as_float(lv_.w << 16);                      \
        const float l7_ = __uint_as_float(lv_.w & 0xFFFF0000u);              \
        float z_, p_;                                                        \
        z_ = l0_ + r0; z_ = fmaxf(z_, NEG_SLOPE * z_); p_  = z_ * a0;        \
        z_ = l1_ + r1; z_ = fmaxf(z_, NEG_SLOPE * z_); p_ += z_ * a1;        \
        z_ = l2_ + r2; z_ = fmaxf(z_, NEG_SLOPE * z_); p_ += z_ * a2;        \
        z_ = l3_ + r3; z_ = fmaxf(z_, NEG_SLOPE * z_); p_ += z_ * a3;        \
        z_ = l4_ + r4; z_ = fmaxf(z_, NEG_SLOPE * z_); p_ += z_ * a4;        \
        z_ = l5_ + r5; z_ = fmaxf(z_, NEG_SLOPE * z_); p_ += z_ * a5;        \
        z_ = l6_ + r6; z_ = fmaxf(z_, NEG_SLOPE * z_); p_ += z_ * a6;        \
        z_ = l7_ + r7; z_ = fmaxf(z_, NEG_SLOPE * z_); p_ += z_ * a7;        \
        p_ += __shfl_xor(p_, 1, 64);                                         \
        const float e_ = exp2f(p_ - mx) * (GATE);                            \
        s += e_;                                                             \
        c0 += e_ * l0_; c1 += e_ * l1_; c2 += e_ * l2_; c3 += e_ * l3_;      \
        c4 += e_ * l4_; c5 += e_ * l5_; c6 += e_ * l6_; c7 += e_ * l7_;      \
    }

// ---------------- fused gather v4: bf16 features, 4 edges/wave -----------------
template <bool HEAD>
__global__ __launch_bounds__(256) void node_gather(const unsigned short* __restrict__ xl,
                                                   const unsigned short* __restrict__ xr,
                                                   const float* __restrict__ att,
                                                   const int* __restrict__ adj,
                                                   const int* __restrict__ cnt,
                                                   const float* __restrict__ bias,
                                                   unsigned short* __restrict__ outC,
                                                   const float* __restrict__ headW,
                                                   const float* __restrict__ headB,
                                                   float* __restrict__ outH,
                                                   int n, int pad) {
    __shared__ float WsL[HEAD ? FDIM * NCLS : 1];             // 8 KB if HEAD
    __shared__ __align__(16) float stage[HEAD ? 4 : 1][FDIM]; // 2 KB if HEAD
    const int t = threadIdx.x;
    if (HEAD) {
        for (int i = t; i < FDIM * NCLS; i += 256) WsL[i] = headW[i];
        __syncthreads();
    }
    const int lane = t & 63;
    const int w = t >> 6;
    const int node = blockIdx.x * 4 + w;
    if (node >= n) return;
    const int g = lane >> 4;           // edge group 0..3
    const int sub = lane & 15;
    const int col = sub * 8;           // 8 channels per lane
    float a0, a1, a2, a3, a4, a5, a6, a7;
    {
        const float4 v0 = *(const float4*)(att + col);
        const float4 v1 = *(const float4*)(att + col + 4);
        a0 = v0.x * LOG2E; a1 = v0.y * LOG2E; a2 = v0.z * LOG2E; a3 = v0.w * LOG2E;
        a4 = v1.x * LOG2E; a5 = v1.y * LOG2E; a6 = v1.z * LOG2E; a7 = v1.w * LOG2E;
    }
    float r0, r1, r2, r3, r4, r5, r6, r7;
    float sl0, sl1, sl2, sl3, sl4, sl5, sl6, sl7;
    {
        const uint4 rv = *(const uint4*)(xr + (size_t)node * FDIM + col);
        r0 = __uint_as_float(rv.x << 16); r1 = __uint_as_float(rv.x & 0xFFFF0000u);
        r2 = __uint_as_float(rv.y << 16); r3 = __uint_as_float(rv.y & 0xFFFF0000u);
        r4 = __uint_as_float(rv.z << 16); r5 = __uint_as_float(rv.z & 0xFFFF0000u);
        r6 = __uint_as_float(rv.w << 16); r7 = __uint_as_float(rv.w & 0xFFFF0000u);
        const uint4 lv = *(const uint4*)(xl + (size_t)node * FDIM + col);
        sl0 = __uint_as_float(lv.x << 16); sl1 = __uint_as_float(lv.x & 0xFFFF0000u);
        sl2 = __uint_as_float(lv.y << 16); sl3 = __uint_as_float(lv.y & 0xFFFF0000u);
        sl4 = __uint_as_float(lv.z << 16); sl5 = __uint_as_float(lv.z & 0xFFFF0000u);
        sl6 = __uint_as_float(lv.w << 16); sl7 = __uint_as_float(lv.w & 0xFFFF0000u);
    }
    // self-loop logit = fixed softmax shift (depends only on sub -> same per group)
    float mx;
    {
        float z, p;
        z = sl0 + r0; z = fmaxf(z, NEG_SLOPE * z); p  = z * a0;
        z = sl1 + r1; z = fmaxf(z, NEG_SLOPE * z); p += z * a1;
        z = sl2 + r2; z = fmaxf(z, NEG_SLOPE * z); p += z * a2;
        z = sl3 + r3; z = fmaxf(z, NEG_SLOPE * z); p += z * a3;
        z = sl4 + r4; z = fmaxf(z, NEG_SLOPE * z); p += z * a4;
        z = sl5 + r5; z = fmaxf(z, NEG_SLOPE * z); p += z * a5;
        z = sl6 + r6; z = fmaxf(z, NEG_SLOPE * z); p += z * a6;
        z = sl7 + r7; z = fmaxf(z, NEG_SLOPE * z); p += z * a7;
        p += __shfl_xor(p, 1, 64);
        mx = p;
    }
    // group 0 seeded with the self edge
    float s, c0, c1, c2, c3, c4, c5, c6, c7;
    if (g == 0) { s = 1.f; c0 = sl0; c1 = sl1; c2 = sl2; c3 = sl3;
                  c4 = sl4; c5 = sl5; c6 = sl6; c7 = sl7; }
    else        { s = 0.f; c0 = c1 = c2 = c3 = c4 = c5 = c6 = c7 = 0.f; }

    const int* ap = adj + (size_t)node * pad;
    const int deg = min(cnt[node], pad);
    int j = 0;
    for (; j + 8 <= deg; j += 8) {       // 2 edges per group per iter
        const int e0 = ap[j + g];
        const int e1 = ap[j + 4 + g];
        GATHER_EDGE4(e0, 1.f)
        GATHER_EDGE4(e1, 1.f)
    }
    for (; j < deg; j += 4) {
        const int idx = j + g;
        const int e0 = (idx < deg) ? ap[idx] : ap[deg - 1];
        const float gate = (idx < deg) ? 1.f : 0.f;
        GATHER_EDGE4(e0, gate)
    }
    // merge the 4 groups (same channels, disjoint edge subsets)
    s  += __shfl_xor(s, 16, 64);  s  += __shfl_xor(s, 32, 64);
    c0 += __shfl_xor(c0, 16, 64); c0 += __shfl_xor(c0, 32, 64);
    c1 += __shfl_xor(c1, 16, 64); c1 += __shfl_xor(c1, 32, 64);
    c2 += __shfl_xor(c2, 16, 64); c2 += __shfl_xor(c2, 32, 64);
    c3 += __shfl_xor(c3, 16, 64); c3 += __shfl_xor(c3, 32, 64);
    c4 += __shfl_xor(c4, 16, 64); c4 += __shfl_xor(c4, 32, 64);
    c5 += __shfl_xor(c5, 16, 64); c5 += __shfl_xor(c5, 32, 64);
    c6 += __shfl_xor(c6, 16, 64); c6 += __shfl_xor(c6, 32, 64);
    c7 += __shfl_xor(c7, 16, 64); c7 += __shfl_xor(c7, 32, 64);

    const float inv = 1.f / (s + 1e-16f);
    float o0, o1, o2, o3, o4, o5, o6, o7;
    {
        const float4 b0 = *(const float4*)(bias + col);
        const float4 b1 = *(const float4*)(bias + col + 4);
        o0 = fmaxf(c0 * inv + b0.x, 0.f); o1 = fmaxf(c1 * inv + b0.y, 0.f);
        o2 = fmaxf(c2 * inv + b0.z, 0.f); o3 = fmaxf(c3 * inv + b0.w, 0.f);
        o4 = fmaxf(c4 * inv + b1.x, 0.f); o5 = fmaxf(c5 * inv + b1.y, 0.f);
        o6 = fmaxf(c6 * inv + b1.z, 0.f); o7 = fmaxf(c7 * inv + b1.w, 0.f);
    }

    if (!HEAD) {
        if (g == 0) {
            union { unsigned short us[8]; uint4 u4; } pk;
            pk.us[0] = f2bf(o0); pk.us[1] = f2bf(o1);
            pk.us[2] = f2bf(o2); pk.us[3] = f2bf(o3);
            pk.us[4] = f2bf(o4); pk.us[5] = f2bf(o5);
            pk.us[6] = f2bf(o6); pk.us[7] = f2bf(o7);
            *(uint4*)(outC + (size_t)node * FDIM + col) = pk.u4;
        }
        return;
    }
    // ---- fused head: wave-local LDS transpose, 128->16 dot, log_softmax ----
    if (g == 0) {
        *(float4*)&stage[w][col]     = make_float4(o0, o1, o2, o3);
        *(float4*)&stage[w][col + 4] = make_float4(o4, o5, o6, o7);
    }
    const int cls = lane & 15;
    const int q = lane >> 4;          // quarter of the k-range
    float acc = 0.f;
#pragma unroll
    for (int k = 0; k < 32; k++)
        acc += stage[w][q * 32 + k] * WsL[(q * 32 + k) * NCLS + cls];
    acc += __shfl_xor(acc, 16, 64);
    acc += __shfl_xor(acc, 32, 64);
    acc += headB[cls];
    float m2 = acc;
    m2 = fmaxf(m2, __shfl_xor(m2, 8, 64));
    m2 = fmaxf(m2, __shfl_xor(m2, 4, 64));
    m2 = fmaxf(m2, __shfl_xor(m2, 2, 64));
    m2 = fmaxf(m2, __shfl_xor(m2, 1, 64));
    float sm = __expf(acc - m2);
    sm += __shfl_xor(sm, 8, 64);
    sm += __shfl_xor(sm, 4, 64);
    sm += __shfl_xor(sm, 2, 64);
    sm += __shfl_xor(sm, 1, 64);
    if (lane < 16)
        outH[(size_t)node * NCLS + cls] = acc - m2 - __logf(sm);
}

// ==============================================================================
extern "C" void kernel_launch(void* const* d_in, const int* in_sizes, int n_in,
                              void* d_out, int out_size, void* d_ws, size_t ws_size,
                              hipStream_t stream) {
    const float* x    = (const float*)d_in[0];
    const int*   edge = (const int*)d_in[1];
    const float* Wl1  = (const float*)d_in[2];
    const float* Wr1  = (const float*)d_in[3];
    const float* att1 = (const float*)d_in[4];
    const float* b1   = (const float*)d_in[5];
    const float* Wl2  = (const float*)d_in[6];
    const float* Wr2  = (const float*)d_in[7];
    const float* att2 = (const float*)d_in[8];
    const float* b2   = (const float*)d_in[9];
    const float* Wlin = (const float*)d_in[10];
    const float* blin = (const float*)d_in[11];

    const int N = in_sizes[0] / FDIM;        // 50000
    const int E0 = in_sizes[1] / 2;          // 1600000
    const int* srcs = edge;
    const int* dsts = edge + E0;

    // padded adjacency: in-degree is ~Poisson(32); PAD=96 is ~1e-13-safe.
    int PAD = 96;
    {
        size_t need = (size_t)3 * N * FDIM * 2 + (size_t)N * 4 + (size_t)N * PAD * 4;
        if (need > ws_size) PAD = 72;   // still ~1e-9-safe
    }

    unsigned short* A = (unsigned short*)d_ws;      // xl bf16  N*128
    unsigned short* B = A + (size_t)N * FDIM;       // xr bf16  N*128
    unsigned short* C = B + (size_t)N * FDIM;       // conv1 out bf16 N*128
    int* cnt   = (int*)(C + (size_t)N * FDIM);      // N
    int* adj   = cnt + N;                           // N*PAD

    const int GB = (N + 127) / 128;          // 391 super-tile blocks per W side
    const int G  = 2 * GB;                   // 782 gemm blocks
    const int SB = (G + 2) / 3;              // 261 scatter blocks, 1:3 interleave
    const int node_blocks = (N + 3) / 4;

    hipMemsetAsync(cnt, 0, (size_t)N * sizeof(int), stream);

    // ---- layer 1: dual MFMA-GEMM + interleaved CSR scatter (grid = 4*SB) ----
    gemm_csr<<<4 * SB, 256, 0, stream>>>(
        x, nullptr, Wl1, Wr1, A, B, N, srcs, dsts, cnt, adj, E0, PAD, GB, SB);
    node_gather<false><<<node_blocks, 256, 0, stream>>>(
        A, B, att1, adj, cnt, b1, C, nullptr, nullptr, nullptr, N, PAD);

    // ---- layer 2 (X = bf16 conv1 output) ----
    gemm_csr<<<G, 256, 0, stream>>>(
        nullptr, C, Wl2, Wr2, A, B, N, nullptr, nullptr, nullptr, nullptr, 0, PAD, GB, 0);
    node_gather<true><<<node_blocks, 256, 0, stream>>>(
        A, B, att2, adj, cnt, b2, nullptr, Wlin, blin, (float*)d_out, N, PAD);
}

// Round 14
// 365.461 us; speedup vs baseline: 1.1600x; 1.1600x over previous
//
#include <hip/hip_runtime.h>

#define HEADS 8
#define FDIM 128          // HEADS*16 = feature width of both conv layers
#define NCLS 16
#define NEG_SLOPE 0.2f
#define LOG2E 1.4426950408889634f

typedef __attribute__((ext_vector_type(8))) short bf16x8;
typedef __attribute__((ext_vector_type(4))) float f32x4;

__device__ __forceinline__ unsigned short f2bf(float f) {
    unsigned u = __float_as_uint(f);
    unsigned r = u + 0x7FFFu + ((u >> 16) & 1u);   // round-to-nearest-even
    return (unsigned short)(r >> 16);
}

// ---------------- fused: dual MFMA-GEMM + padded-CSR build ---------------------
// Operand-swapped MFMA: acc = mfma(w_frag, x_frag) -> lane (q,jd) accumulates
// Y[row=jd][cols ct*16+q*4..+3]. R13 lesson: writing those 8B chunks (or R12's
// 2B scalars) straight to global costs ~5x HBM write amplification (121 MB for
// a 25.6 MB Y; partial-line sectors bypass L3). Fix: pack acc into an LDS out
// tile (wave-private -> no barrier), read back linearly, store uint4 with 16
// consecutive lanes covering a full 256B row (same clean pattern that gives
// node_gather 3.5 MB WRITE for a 12.8 MB payload).
// Roles when SB>0: x%5==4 -> CSR scatter block (interleaved, co-resident).
__global__ __launch_bounds__(256) void gemm_csr(const float* __restrict__ Xf,
                                                const unsigned short* __restrict__ Xb,
                                                const float* __restrict__ W0,
                                                const float* __restrict__ W1,
                                                unsigned short* __restrict__ Y0,
                                                unsigned short* __restrict__ Y1,
                                                int n,
                                                const int* __restrict__ srcs,
                                                const int* __restrict__ dsts,
                                                int* __restrict__ cnt,
                                                int* __restrict__ adj,
                                                int E0, int pad, int GB, int SB) {
    __shared__ __align__(16) unsigned short ws[8 * 4 * 64 * 8];   // 32 KB
    __shared__ __align__(16) unsigned short ys[64 * 132];         // 16.5 KB out tile
    const int t = threadIdx.x;
    const int x = blockIdx.x;
    int gIdx;
    if (SB > 0) {
        if ((x % 5) == 4) {          // scatter role, interleaved
            int i = (x / 5) * 256 + t;
            const int stride = SB * 256;
            for (; i < E0; i += stride) {
                const int d = dsts[i];
                const int rk = atomicAdd(&cnt[d], 1);
                if (rk < pad) adj[(size_t)d * pad + rk] = srcs[i];
            }
            return;
        }
        gIdx = (x / 5) * 4 + (x % 5);
    } else {
        gIdx = x;
    }
    if (gIdx >= 2 * GB) return;
    const int side = (gIdx >= GB) ? 1 : 0;
    const float* W = side ? W1 : W0;
    unsigned short* Y = side ? Y1 : Y0;
    const int nb = (side ? gIdx - GB : gIdx) * 64;

    // ---- stage W (128x128) as bf16 fragments, once per block ----
#pragma unroll
    for (int i = 0; i < 16; i++) {
        const int f = t + i * 256;         // k = f>>5, n4 = f&31
        const int k = f >> 5, n4 = f & 31;
        const float4 v = *(const float4*)(W + k * 128 + n4 * 4);
        const int kc = k >> 5, q = (k >> 3) & 3, j = k & 7;
        const float vv[4] = {v.x, v.y, v.z, v.w};
#pragma unroll
        for (int e = 0; e < 4; e++) {
            const int nn = n4 * 4 + e;
            ws[((((nn >> 4) * 4 + kc) * 64 + q * 16 + (nn & 15)) << 3) + j] = f2bf(vv[e]);
        }
    }
    __syncthreads();

    const int w = t >> 6, lane = t & 63;
    const int q = lane >> 4, jd = lane & 15;
    const bf16x8* wb = (const bf16x8*)ws;

    const int row = nb + w * 16 + jd;       // the X/Y row this lane owns
    bf16x8 bx[4];
#pragma unroll
    for (int kc = 0; kc < 4; kc++) bx[kc] = (bf16x8){0,0,0,0,0,0,0,0};
    if (row < n) {
        if (Xb) {
            const unsigned short* xp = Xb + (size_t)row * 128 + q * 8;
#pragma unroll
            for (int kc = 0; kc < 4; kc++) bx[kc] = *(const bf16x8*)(xp + kc * 32);
        } else {
            const float* xp = Xf + (size_t)row * 128 + q * 8;
#pragma unroll
            for (int kc = 0; kc < 4; kc++) {
                const float4 v0 = *(const float4*)(xp + kc * 32);
                const float4 v1 = *(const float4*)(xp + kc * 32 + 4);
                union { unsigned short us[8]; bf16x8 b; } pk;
                pk.us[0] = f2bf(v0.x); pk.us[1] = f2bf(v0.y);
                pk.us[2] = f2bf(v0.z); pk.us[3] = f2bf(v0.w);
                pk.us[4] = f2bf(v1.x); pk.us[5] = f2bf(v1.y);
                pk.us[6] = f2bf(v1.z); pk.us[7] = f2bf(v1.w);
                bx[kc] = pk.b;
            }
        }
    }
    f32x4 acc[8];
#pragma unroll
    for (int i = 0; i < 8; i++) acc[i] = (f32x4){0.f, 0.f, 0.f, 0.f};
#pragma unroll
    for (int kc = 0; kc < 4; kc++) {
#pragma unroll
        for (int ct = 0; ct < 8; ct++)
            acc[ct] = __builtin_amdgcn_mfma_f32_16x16x32_bf16(
                wb[(ct * 4 + kc) * 64 + lane], bx[kc], acc[ct], 0, 0, 0);
    }
    // ---- epilogue: acc -> LDS tile (wave-private, 264B row stride) ----
    {
        unsigned short* yrow = ys + (w * 16 + jd) * 132;
#pragma unroll
        for (int ct = 0; ct < 8; ct++) {
            union { unsigned short us[4]; uint2 u2; } pk;
            pk.us[0] = f2bf(acc[ct][0]); pk.us[1] = f2bf(acc[ct][1]);
            pk.us[2] = f2bf(acc[ct][2]); pk.us[3] = f2bf(acc[ct][3]);
            *(uint2*)(yrow + ct * 16 + q * 4) = pk.u2;
        }
    }
    // ---- linear read-back + full-line global store (16 lanes = one 256B row)
    {
        const int rr = lane >> 4;          // row within 4-row group
        const int ch = lane & 15;          // 16B chunk within row
#pragma unroll
        for (int i = 0; i < 4; i++) {
            const int lrow = w * 16 + i * 4 + rr;
            const int grow = nb + lrow;
            const uint4 v = *(const uint4*)(ys + lrow * 132 + ch * 8);
            if (grow < n)
                *(uint4*)(Y + (size_t)grow * 128 + ch * 8) = v;
        }
    }
}

// one edge-step for gather v4 (4 edges/wave, 16-lane groups, 8 ch/lane)
#define GATHER_EDGE4(SRC, GATE)                                              \
    {                                                                        \
        const uint4 lv_ = *(const uint4*)(xl + (size_t)(SRC) * FDIM + col);  \
        const float l0_ = __uint_as_float(lv_.x << 16);                      \
        const float l1_ = __uint_as_float(lv_.x & 0xFFFF0000u);              \
        const float l2_ = __uint_as_float(lv_.y << 16);                      \
        const float l3_ = __uint_as_float(lv_.y & 0xFFFF0000u);              \
        const float l4_ = __uint_as_float(lv_.z << 16);                      \
        const float l5_ = __uint_as_float(lv_.z & 0xFFFF0000u);              \
        const float l6_ = __uint_as_float(lv_.w << 16);                      \
        const float l7_ = __uint_as_float(lv_.w & 0xFFFF0000u);              \
        float z_, p_;                                                        \
        z_ = l0_ + r0; z_ = fmaxf(z_, NEG_SLOPE * z_); p_  = z_ * a0;        \
        z_ = l1_ + r1; z_ = fmaxf(z_, NEG_SLOPE * z_); p_ += z_ * a1;        \
        z_ = l2_ + r2; z_ = fmaxf(z_, NEG_SLOPE * z_); p_ += z_ * a2;        \
        z_ = l3_ + r3; z_ = fmaxf(z_, NEG_SLOPE * z_); p_ += z_ * a3;        \
        z_ = l4_ + r4; z_ = fmaxf(z_, NEG_SLOPE * z_); p_ += z_ * a4;        \
        z_ = l5_ + r5; z_ = fmaxf(z_, NEG_SLOPE * z_); p_ += z_ * a5;        \
        z_ = l6_ + r6; z_ = fmaxf(z_, NEG_SLOPE * z_); p_ += z_ * a6;        \
        z_ = l7_ + r7; z_ = fmaxf(z_, NEG_SLOPE * z_); p_ += z_ * a7;        \
        p_ += __shfl_xor(p_, 1, 64);                                         \
        const float e_ = exp2f(p_ - mx) * (GATE);                            \
        s += e_;                                                             \
        c0 += e_ * l0_; c1 += e_ * l1_; c2 += e_ * l2_; c3 += e_ * l3_;      \
        c4 += e_ * l4_; c5 += e_ * l5_; c6 += e_ * l6_; c7 += e_ * l7_;      \
    }

// ---------------- fused gather v4: bf16 features, 4 edges/wave -----------------
template <bool HEAD>
__global__ __launch_bounds__(256) void node_gather(const unsigned short* __restrict__ xl,
                                                   const unsigned short* __restrict__ xr,
                                                   const float* __restrict__ att,
                                                   const int* __restrict__ adj,
                                                   const int* __restrict__ cnt,
                                                   const float* __restrict__ bias,
                                                   unsigned short* __restrict__ outC,
                                                   const float* __restrict__ headW,
                                                   const float* __restrict__ headB,
                                                   float* __restrict__ outH,
                                                   int n, int pad) {
    __shared__ float WsL[HEAD ? FDIM * NCLS : 1];             // 8 KB if HEAD
    __shared__ __align__(16) float stage[HEAD ? 4 : 1][FDIM]; // 2 KB if HEAD
    const int t = threadIdx.x;
    if (HEAD) {
        for (int i = t; i < FDIM * NCLS; i += 256) WsL[i] = headW[i];
        __syncthreads();
    }
    const int lane = t & 63;
    const int w = t >> 6;
    const int node = blockIdx.x * 4 + w;
    if (node >= n) return;
    const int g = lane >> 4;           // edge group 0..3
    const int sub = lane & 15;
    const int col = sub * 8;           // 8 channels per lane
    float a0, a1, a2, a3, a4, a5, a6, a7;
    {
        const float4 v0 = *(const float4*)(att + col);
        const float4 v1 = *(const float4*)(att + col + 4);
        a0 = v0.x * LOG2E; a1 = v0.y * LOG2E; a2 = v0.z * LOG2E; a3 = v0.w * LOG2E;
        a4 = v1.x * LOG2E; a5 = v1.y * LOG2E; a6 = v1.z * LOG2E; a7 = v1.w * LOG2E;
    }
    float r0, r1, r2, r3, r4, r5, r6, r7;
    float sl0, sl1, sl2, sl3, sl4, sl5, sl6, sl7;
    {
        const uint4 rv = *(const uint4*)(xr + (size_t)node * FDIM + col);
        r0 = __uint_as_float(rv.x << 16); r1 = __uint_as_float(rv.x & 0xFFFF0000u);
        r2 = __uint_as_float(rv.y << 16); r3 = __uint_as_float(rv.y & 0xFFFF0000u);
        r4 = __uint_as_float(rv.z << 16); r5 = __uint_as_float(rv.z & 0xFFFF0000u);
        r6 = __uint_as_float(rv.w << 16); r7 = __uint_as_float(rv.w & 0xFFFF0000u);
        const uint4 lv = *(const uint4*)(xl + (size_t)node * FDIM + col);
        sl0 = __uint_as_float(lv.x << 16); sl1 = __uint_as_float(lv.x & 0xFFFF0000u);
        sl2 = __uint_as_float(lv.y << 16); sl3 = __uint_as_float(lv.y & 0xFFFF0000u);
        sl4 = __uint_as_float(lv.z << 16); sl5 = __uint_as_float(lv.z & 0xFFFF0000u);
        sl6 = __uint_as_float(lv.w << 16); sl7 = __uint_as_float(lv.w & 0xFFFF0000u);
    }
    // self-loop logit = fixed softmax shift (depends only on sub -> same per group)
    float mx;
    {
        float z, p;
        z = sl0 + r0; z = fmaxf(z, NEG_SLOPE * z); p  = z * a0;
        z = sl1 + r1; z = fmaxf(z, NEG_SLOPE * z); p += z * a1;
        z = sl2 + r2; z = fmaxf(z, NEG_SLOPE * z); p += z * a2;
        z = sl3 + r3; z = fmaxf(z, NEG_SLOPE * z); p += z * a3;
        z = sl4 + r4; z = fmaxf(z, NEG_SLOPE * z); p += z * a4;
        z = sl5 + r5; z = fmaxf(z, NEG_SLOPE * z); p += z * a5;
        z = sl6 + r6; z = fmaxf(z, NEG_SLOPE * z); p += z * a6;
        z = sl7 + r7; z = fmaxf(z, NEG_SLOPE * z); p += z * a7;
        p += __shfl_xor(p, 1, 64);
        mx = p;
    }
    // group 0 seeded with the self edge
    float s, c0, c1, c2, c3, c4, c5, c6, c7;
    if (g == 0) { s = 1.f; c0 = sl0; c1 = sl1; c2 = sl2; c3 = sl3;
                  c4 = sl4; c5 = sl5; c6 = sl6; c7 = sl7; }
    else        { s = 0.f; c0 = c1 = c2 = c3 = c4 = c5 = c6 = c7 = 0.f; }

    const int* ap = adj + (size_t)node * pad;
    const int deg = min(cnt[node], pad);
    int j = 0;
    for (; j + 8 <= deg; j += 8) {       // 2 edges per group per iter
        const int e0 = ap[j + g];
        const int e1 = ap[j + 4 + g];
        GATHER_EDGE4(e0, 1.f)
        GATHER_EDGE4(e1, 1.f)
    }
    for (; j < deg; j += 4) {
        const int idx = j + g;
        const int e0 = (idx < deg) ? ap[idx] : ap[deg - 1];
        const float gate = (idx < deg) ? 1.f : 0.f;
        GATHER_EDGE4(e0, gate)
    }
    // merge the 4 groups (same channels, disjoint edge subsets)
    s  += __shfl_xor(s, 16, 64);  s  += __shfl_xor(s, 32, 64);
    c0 += __shfl_xor(c0, 16, 64); c0 += __shfl_xor(c0, 32, 64);
    c1 += __shfl_xor(c1, 16, 64); c1 += __shfl_xor(c1, 32, 64);
    c2 += __shfl_xor(c2, 16, 64); c2 += __shfl_xor(c2, 32, 64);
    c3 += __shfl_xor(c3, 16, 64); c3 += __shfl_xor(c3, 32, 64);
    c4 += __shfl_xor(c4, 16, 64); c4 += __shfl_xor(c4, 32, 64);
    c5 += __shfl_xor(c5, 16, 64); c5 += __shfl_xor(c5, 32, 64);
    c6 += __shfl_xor(c6, 16, 64); c6 += __shfl_xor(c6, 32, 64);
    c7 += __shfl_xor(c7, 16, 64); c7 += __shfl_xor(c7, 32, 64);

    const float inv = 1.f / (s + 1e-16f);
    float o0, o1, o2, o3, o4, o5, o6, o7;
    {
        const float4 b0 = *(const float4*)(bias + col);
        const float4 b1 = *(const float4*)(bias + col + 4);
        o0 = fmaxf(c0 * inv + b0.x, 0.f); o1 = fmaxf(c1 * inv + b0.y, 0.f);
        o2 = fmaxf(c2 * inv + b0.z, 0.f); o3 = fmaxf(c3 * inv + b0.w, 0.f);
        o4 = fmaxf(c4 * inv + b1.x, 0.f); o5 = fmaxf(c5 * inv + b1.y, 0.f);
        o6 = fmaxf(c6 * inv + b1.z, 0.f); o7 = fmaxf(c7 * inv + b1.w, 0.f);
    }

    if (!HEAD) {
        if (g == 0) {
            union { unsigned short us[8]; uint4 u4; } pk;
            pk.us[0] = f2bf(o0); pk.us[1] = f2bf(o1);
            pk.us[2] = f2bf(o2); pk.us[3] = f2bf(o3);
            pk.us[4] = f2bf(o4); pk.us[5] = f2bf(o5);
            pk.us[6] = f2bf(o6); pk.us[7] = f2bf(o7);
            *(uint4*)(outC + (size_t)node * FDIM + col) = pk.u4;
        }
        return;
    }
    // ---- fused head: wave-local LDS transpose, 128->16 dot, log_softmax ----
    if (g == 0) {
        *(float4*)&stage[w][col]     = make_float4(o0, o1, o2, o3);
        *(float4*)&stage[w][col + 4] = make_float4(o4, o5, o6, o7);
    }
    const int cls = lane & 15;
    const int q = lane >> 4;          // quarter of the k-range
    float acc = 0.f;
#pragma unroll
    for (int k = 0; k < 32; k++)
        acc += stage[w][q * 32 + k] * WsL[(q * 32 + k) * NCLS + cls];
    acc += __shfl_xor(acc, 16, 64);
    acc += __shfl_xor(acc, 32, 64);
    acc += headB[cls];
    float m2 = acc;
    m2 = fmaxf(m2, __shfl_xor(m2, 8, 64));
    m2 = fmaxf(m2, __shfl_xor(m2, 4, 64));
    m2 = fmaxf(m2, __shfl_xor(m2, 2, 64));
    m2 = fmaxf(m2, __shfl_xor(m2, 1, 64));
    float sm = __expf(acc - m2);
    sm += __shfl_xor(sm, 8, 64);
    sm += __shfl_xor(sm, 4, 64);
    sm += __shfl_xor(sm, 2, 64);
    sm += __shfl_xor(sm, 1, 64);
    if (lane < 16)
        outH[(size_t)node * NCLS + cls] = acc - m2 - __logf(sm);
}

// ==============================================================================
extern "C" void kernel_launch(void* const* d_in, const int* in_sizes, int n_in,
                              void* d_out, int out_size, void* d_ws, size_t ws_size,
                              hipStream_t stream) {
    const float* x    = (const float*)d_in[0];
    const int*   edge = (const int*)d_in[1];
    const float* Wl1  = (const float*)d_in[2];
    const float* Wr1  = (const float*)d_in[3];
    const float* att1 = (const float*)d_in[4];
    const float* b1   = (const float*)d_in[5];
    const float* Wl2  = (const float*)d_in[6];
    const float* Wr2  = (const float*)d_in[7];
    const float* att2 = (const float*)d_in[8];
    const float* b2   = (const float*)d_in[9];
    const float* Wlin = (const float*)d_in[10];
    const float* blin = (const float*)d_in[11];

    const int N = in_sizes[0] / FDIM;        // 50000
    const int E0 = in_sizes[1] / 2;          // 1600000
    const int* srcs = edge;
    const int* dsts = edge + E0;

    // padded adjacency: in-degree is ~Poisson(32); PAD=96 is ~1e-13-safe.
    int PAD = 96;
    {
        size_t need = (size_t)3 * N * FDIM * 2 + (size_t)N * 4 + (size_t)N * PAD * 4;
        if (need > ws_size) PAD = 72;   // still ~1e-9-safe
    }

    unsigned short* A = (unsigned short*)d_ws;      // xl bf16  N*128
    unsigned short* B = A + (size_t)N * FDIM;       // xr bf16  N*128
    unsigned short* C = B + (size_t)N * FDIM;       // conv1 out bf16 N*128
    int* cnt   = (int*)(C + (size_t)N * FDIM);      // N
    int* adj   = cnt + N;                           // N*PAD

    const int GB = (N + 63) / 64;            // 782 tiles per W side
    const int G  = 2 * GB;                   // 1564 gemm blocks
    const int SB = (G + 3) / 4;              // 391 scatter blocks, 1:4 interleave
    const int node_blocks = (N + 3) / 4;

    hipMemsetAsync(cnt, 0, (size_t)N * sizeof(int), stream);

    // ---- layer 1: dual MFMA-GEMM + interleaved CSR scatter (grid = 5*SB) ----
    gemm_csr<<<5 * SB, 256, 0, stream>>>(
        x, nullptr, Wl1, Wr1, A, B, N, srcs, dsts, cnt, adj, E0, PAD, GB, SB);
    node_gather<false><<<node_blocks, 256, 0, stream>>>(
        A, B, att1, adj, cnt, b1, C, nullptr, nullptr, nullptr, N, PAD);

    // ---- layer 2 (X = bf16 conv1 output) ----
    gemm_csr<<<G, 256, 0, stream>>>(
        nullptr, C, Wl2, Wr2, A, B, N, nullptr, nullptr, nullptr, nullptr, 0, PAD, GB, 0);
    node_gather<true><<<node_blocks, 256, 0, stream>>>(
        A, B, att2, adj, cnt, b2, nullptr, Wlin, blin, (float*)d_out, N, PAD);
}

// Round 15
// 363.164 us; speedup vs baseline: 1.1673x; 1.0063x over previous
//
#include <hip/hip_runtime.h>

#define HEADS 8
#define FDIM 128          // HEADS*16 = feature width of both conv layers
#define NCLS 16
#define NEG_SLOPE 0.2f
#define LOG2E 1.4426950408889634f

typedef __attribute__((ext_vector_type(8))) short bf16x8;
typedef __attribute__((ext_vector_type(4))) float f32x4;

__device__ __forceinline__ unsigned short f2bf(float f) {
    unsigned u = __float_as_uint(f);
    unsigned r = u + 0x7FFFu + ((u >> 16) & 1u);   // round-to-nearest-even
    return (unsigned short)(r >> 16);
}

// ---------------- prep: swizzle all 4 W matrices into fragment layout + cnt=0 --
// R14 lesson: doing the row-major -> fragment scatter into LDS per gemm block
// costs ~32-way ds_write_b16 conflicts (12.2M conflict cycles). Do the scatter
// ONCE here into global bf16 buffers (4 x 32 KB, write amp irrelevant); gemm
// blocks then stage with a conflict-free linear b128 copy.
__global__ __launch_bounds__(256) void prep(const float* __restrict__ W0,
                                            const float* __restrict__ W1,
                                            const float* __restrict__ W2,
                                            const float* __restrict__ W3,
                                            unsigned short* __restrict__ O,
                                            int* __restrict__ cnt, int n) {
    const int b = blockIdx.x;
    const int t = threadIdx.x;
    if (b < 4) {
        const float* W = b == 0 ? W0 : b == 1 ? W1 : b == 2 ? W2 : W3;
        unsigned short* out = O + b * 16384;
#pragma unroll
        for (int i = 0; i < 16; i++) {
            const int f = t + i * 256;         // k = f>>5, n4 = f&31
            const int k = f >> 5, n4 = f & 31;
            const float4 v = *(const float4*)(W + k * 128 + n4 * 4);
            const int kc = k >> 5, q = (k >> 3) & 3, j = k & 7;
            const float vv[4] = {v.x, v.y, v.z, v.w};
#pragma unroll
            for (int e = 0; e < 4; e++) {
                const int nn = n4 * 4 + e;
                out[((((nn >> 4) * 4 + kc) * 64 + q * 16 + (nn & 15)) << 3) + j] = f2bf(vv[e]);
            }
        }
        return;
    }
    // remaining blocks: zero cnt
    const int stride = (gridDim.x - 4) * 256;
    for (int i = (b - 4) * 256 + t; i < n; i += stride) cnt[i] = 0;
}

// ---------------- fused: dual MFMA-GEMM + padded-CSR build ---------------------
// Operand-swapped MFMA: acc = mfma(w_frag, x_frag) -> lane (q,jd) holds
// Y[row=jd][ct*16+q*4..+3] -> 8 x uint2 stores (back-to-back per line).
// W comes PRE-SWIZZLED (prep kernel): staging = linear float4->b128 copy,
// conflict-free. 2 tiles per block (GB=391/side); scatter interleaved x%5==4.
__global__ __launch_bounds__(256) void gemm_csr(const float* __restrict__ Xf,
                                                const unsigned short* __restrict__ Xb,
                                                const unsigned short* __restrict__ Wsw0,
                                                const unsigned short* __restrict__ Wsw1,
                                                unsigned short* __restrict__ Y0,
                                                unsigned short* __restrict__ Y1,
                                                int n,
                                                const int* __restrict__ srcs,
                                                const int* __restrict__ dsts,
                                                int* __restrict__ cnt,
                                                int* __restrict__ adj,
                                                int E0, int pad, int GB, int SB) {
    __shared__ __align__(16) unsigned short ws[8 * 4 * 64 * 8];   // 32 KB
    const int t = threadIdx.x;
    const int x = blockIdx.x;
    int gIdx;
    if (SB > 0) {
        if ((x % 5) == 4) {          // scatter role, interleaved
            int i = (x / 5) * 256 + t;
            const int stride = SB * 256;
            for (; i < E0; i += stride) {
                const int d = dsts[i];
                const int rk = atomicAdd(&cnt[d], 1);
                if (rk < pad) adj[(size_t)d * pad + rk] = srcs[i];
            }
            return;
        }
        gIdx = (x / 5) * 4 + (x % 5);
    } else {
        gIdx = x;
    }
    if (gIdx >= 2 * GB) return;
    const int side = (gIdx >= GB) ? 1 : 0;
    const unsigned short* Wsw = side ? Wsw1 : Wsw0;
    unsigned short* Y = side ? Y1 : Y0;
    const int bid = side ? gIdx - GB : gIdx;

    // ---- stage pre-swizzled W: linear copy, conflict-free ----
    {
        const uint4* Wv = (const uint4*)Wsw;
        uint4* wv = (uint4*)ws;
#pragma unroll
        for (int i = 0; i < 8; i++) wv[t + i * 256] = Wv[t + i * 256];
    }
    __syncthreads();

    const int w = t >> 6, lane = t & 63;
    const int q = lane >> 4, jd = lane & 15;
    const bf16x8* wb = (const bf16x8*)ws;
    const int Gh = (n + 63) >> 6;

    for (int tile = bid; tile < Gh; tile += GB) {
        const int nb = tile * 64;
        const int row = nb + w * 16 + jd;       // the X/Y row this lane owns
        bf16x8 bx[4];
#pragma unroll
        for (int kc = 0; kc < 4; kc++) bx[kc] = (bf16x8){0,0,0,0,0,0,0,0};
        if (row < n) {
            if (Xb) {
                const unsigned short* xp = Xb + (size_t)row * 128 + q * 8;
#pragma unroll
                for (int kc = 0; kc < 4; kc++) bx[kc] = *(const bf16x8*)(xp + kc * 32);
            } else {
                const float* xp = Xf + (size_t)row * 128 + q * 8;
#pragma unroll
                for (int kc = 0; kc < 4; kc++) {
                    const float4 v0 = *(const float4*)(xp + kc * 32);
                    const float4 v1 = *(const float4*)(xp + kc * 32 + 4);
                    union { unsigned short us[8]; bf16x8 b; } pk;
                    pk.us[0] = f2bf(v0.x); pk.us[1] = f2bf(v0.y);
                    pk.us[2] = f2bf(v0.z); pk.us[3] = f2bf(v0.w);
                    pk.us[4] = f2bf(v1.x); pk.us[5] = f2bf(v1.y);
                    pk.us[6] = f2bf(v1.z); pk.us[7] = f2bf(v1.w);
                    bx[kc] = pk.b;
                }
            }
        }
        f32x4 acc[8];
#pragma unroll
        for (int i = 0; i < 8; i++) acc[i] = (f32x4){0.f, 0.f, 0.f, 0.f};
#pragma unroll
        for (int kc = 0; kc < 4; kc++) {
#pragma unroll
            for (int ct = 0; ct < 8; ct++)
                acc[ct] = __builtin_amdgcn_mfma_f32_16x16x32_bf16(
                    wb[(ct * 4 + kc) * 64 + lane], bx[kc], acc[ct], 0, 0, 0);
        }
        if (row < n) {
            unsigned short* yp = Y + (size_t)row * 128 + q * 4;
#pragma unroll
            for (int ct = 0; ct < 8; ct++) {
                union { unsigned short us[4]; uint2 u2; } pk;
                pk.us[0] = f2bf(acc[ct][0]); pk.us[1] = f2bf(acc[ct][1]);
                pk.us[2] = f2bf(acc[ct][2]); pk.us[3] = f2bf(acc[ct][3]);
                *(uint2*)(yp + ct * 16) = pk.u2;
            }
        }
    }
}

// one edge-step for gather v4 (4 edges/wave, 16-lane groups, 8 ch/lane)
#define GATHER_EDGE4(SRC, GATE)                                              \
    {                                                                        \
        const uint4 lv_ = *(const uint4*)(xl + (size_t)(SRC) * FDIM + col);  \
        const float l0_ = __uint_as_float(lv_.x << 16);                      \
        const float l1_ = __uint_as_float(lv_.x & 0xFFFF0000u);              \
        const float l2_ = __uint_as_float(lv_.y << 16);                      \
        const float l3_ = __uint_as_float(lv_.y & 0xFFFF0000u);              \
        const float l4_ = __uint_as_float(lv_.z << 16);                      \
        const float l5_ = __uint_as_float(lv_.z & 0xFFFF0000u);              \
        const float l6_ = __uint_as_float(lv_.w << 16);                      \
        const float l7_ = __uint_as_float(lv_.w & 0xFFFF0000u);              \
        float z_, p_;                                                        \
        z_ = l0_ + r0; z_ = fmaxf(z_, NEG_SLOPE * z_); p_  = z_ * a0;        \
        z_ = l1_ + r1; z_ = fmaxf(z_, NEG_SLOPE * z_); p_ += z_ * a1;        \
        z_ = l2_ + r2; z_ = fmaxf(z_, NEG_SLOPE * z_); p_ += z_ * a2;        \
        z_ = l3_ + r3; z_ = fmaxf(z_, NEG_SLOPE * z_); p_ += z_ * a3;        \
        z_ = l4_ + r4; z_ = fmaxf(z_, NEG_SLOPE * z_); p_ += z_ * a4;        \
        z_ = l5_ + r5; z_ = fmaxf(z_, NEG_SLOPE * z_); p_ += z_ * a5;        \
        z_ = l6_ + r6; z_ = fmaxf(z_, NEG_SLOPE * z_); p_ += z_ * a6;        \
        z_ = l7_ + r7; z_ = fmaxf(z_, NEG_SLOPE * z_); p_ += z_ * a7;        \
        p_ += __shfl_xor(p_, 1, 64);                                         \
        const float e_ = exp2f(p_ - mx) * (GATE);                            \
        s += e_;                                                             \
        c0 += e_ * l0_; c1 += e_ * l1_; c2 += e_ * l2_; c3 += e_ * l3_;      \
        c4 += e_ * l4_; c5 += e_ * l5_; c6 += e_ * l6_; c7 += e_ * l7_;      \
    }

// ---------------- fused gather v4: bf16 features, 4 edges/wave -----------------
template <bool HEAD>
__global__ __launch_bounds__(256) void node_gather(const unsigned short* __restrict__ xl,
                                                   const unsigned short* __restrict__ xr,
                                                   const float* __restrict__ att,
                                                   const int* __restrict__ adj,
                                                   const int* __restrict__ cnt,
                                                   const float* __restrict__ bias,
                                                   unsigned short* __restrict__ outC,
                                                   const float* __restrict__ headW,
                                                   const float* __restrict__ headB,
                                                   float* __restrict__ outH,
                                                   int n, int pad) {
    __shared__ float WsL[HEAD ? FDIM * NCLS : 1];             // 8 KB if HEAD
    __shared__ __align__(16) float stage[HEAD ? 4 : 1][FDIM]; // 2 KB if HEAD
    const int t = threadIdx.x;
    if (HEAD) {
        for (int i = t; i < FDIM * NCLS; i += 256) WsL[i] = headW[i];
        __syncthreads();
    }
    const int lane = t & 63;
    const int w = t >> 6;
    const int node = blockIdx.x * 4 + w;
    if (node >= n) return;
    const int g = lane >> 4;           // edge group 0..3
    const int sub = lane & 15;
    const int col = sub * 8;           // 8 channels per lane
    float a0, a1, a2, a3, a4, a5, a6, a7;
    {
        const float4 v0 = *(const float4*)(att + col);
        const float4 v1 = *(const float4*)(att + col + 4);
        a0 = v0.x * LOG2E; a1 = v0.y * LOG2E; a2 = v0.z * LOG2E; a3 = v0.w * LOG2E;
        a4 = v1.x * LOG2E; a5 = v1.y * LOG2E; a6 = v1.z * LOG2E; a7 = v1.w * LOG2E;
    }
    float r0, r1, r2, r3, r4, r5, r6, r7;
    float sl0, sl1, sl2, sl3, sl4, sl5, sl6, sl7;
    {
        const uint4 rv = *(const uint4*)(xr + (size_t)node * FDIM + col);
        r0 = __uint_as_float(rv.x << 16); r1 = __uint_as_float(rv.x & 0xFFFF0000u);
        r2 = __uint_as_float(rv.y << 16); r3 = __uint_as_float(rv.y & 0xFFFF0000u);
        r4 = __uint_as_float(rv.z << 16); r5 = __uint_as_float(rv.z & 0xFFFF0000u);
        r6 = __uint_as_float(rv.w << 16); r7 = __uint_as_float(rv.w & 0xFFFF0000u);
        const uint4 lv = *(const uint4*)(xl + (size_t)node * FDIM + col);
        sl0 = __uint_as_float(lv.x << 16); sl1 = __uint_as_float(lv.x & 0xFFFF0000u);
        sl2 = __uint_as_float(lv.y << 16); sl3 = __uint_as_float(lv.y & 0xFFFF0000u);
        sl4 = __uint_as_float(lv.z << 16); sl5 = __uint_as_float(lv.z & 0xFFFF0000u);
        sl6 = __uint_as_float(lv.w << 16); sl7 = __uint_as_float(lv.w & 0xFFFF0000u);
    }
    // self-loop logit = fixed softmax shift (depends only on sub -> same per group)
    float mx;
    {
        float z, p;
        z = sl0 + r0; z = fmaxf(z, NEG_SLOPE * z); p  = z * a0;
        z = sl1 + r1; z = fmaxf(z, NEG_SLOPE * z); p += z * a1;
        z = sl2 + r2; z = fmaxf(z, NEG_SLOPE * z); p += z * a2;
        z = sl3 + r3; z = fmaxf(z, NEG_SLOPE * z); p += z * a3;
        z = sl4 + r4; z = fmaxf(z, NEG_SLOPE * z); p += z * a4;
        z = sl5 + r5; z = fmaxf(z, NEG_SLOPE * z); p += z * a5;
        z = sl6 + r6; z = fmaxf(z, NEG_SLOPE * z); p += z * a6;
        z = sl7 + r7; z = fmaxf(z, NEG_SLOPE * z); p += z * a7;
        p += __shfl_xor(p, 1, 64);
        mx = p;
    }
    // group 0 seeded with the self edge
    float s, c0, c1, c2, c3, c4, c5, c6, c7;
    if (g == 0) { s = 1.f; c0 = sl0; c1 = sl1; c2 = sl2; c3 = sl3;
                  c4 = sl4; c5 = sl5; c6 = sl6; c7 = sl7; }
    else        { s = 0.f; c0 = c1 = c2 = c3 = c4 = c5 = c6 = c7 = 0.f; }

    const int* ap = adj + (size_t)node * pad;
    const int deg = min(cnt[node], pad);
    int j = 0;
    for (; j + 8 <= deg; j += 8) {       // 2 edges per group per iter
        const int e0 = ap[j + g];
        const int e1 = ap[j + 4 + g];
        GATHER_EDGE4(e0, 1.f)
        GATHER_EDGE4(e1, 1.f)
    }
    for (; j < deg; j += 4) {
        const int idx = j + g;
        const int e0 = (idx < deg) ? ap[idx] : ap[deg - 1];
        const float gate = (idx < deg) ? 1.f : 0.f;
        GATHER_EDGE4(e0, gate)
    }
    // merge the 4 groups (same channels, disjoint edge subsets)
    s  += __shfl_xor(s, 16, 64);  s  += __shfl_xor(s, 32, 64);
    c0 += __shfl_xor(c0, 16, 64); c0 += __shfl_xor(c0, 32, 64);
    c1 += __shfl_xor(c1, 16, 64); c1 += __shfl_xor(c1, 32, 64);
    c2 += __shfl_xor(c2, 16, 64); c2 += __shfl_xor(c2, 32, 64);
    c3 += __shfl_xor(c3, 16, 64); c3 += __shfl_xor(c3, 32, 64);
    c4 += __shfl_xor(c4, 16, 64); c4 += __shfl_xor(c4, 32, 64);
    c5 += __shfl_xor(c5, 16, 64); c5 += __shfl_xor(c5, 32, 64);
    c6 += __shfl_xor(c6, 16, 64); c6 += __shfl_xor(c6, 32, 64);
    c7 += __shfl_xor(c7, 16, 64); c7 += __shfl_xor(c7, 32, 64);

    const float inv = 1.f / (s + 1e-16f);
    float o0, o1, o2, o3, o4, o5, o6, o7;
    {
        const float4 b0 = *(const float4*)(bias + col);
        const float4 b1 = *(const float4*)(bias + col + 4);
        o0 = fmaxf(c0 * inv + b0.x, 0.f); o1 = fmaxf(c1 * inv + b0.y, 0.f);
        o2 = fmaxf(c2 * inv + b0.z, 0.f); o3 = fmaxf(c3 * inv + b0.w, 0.f);
        o4 = fmaxf(c4 * inv + b1.x, 0.f); o5 = fmaxf(c5 * inv + b1.y, 0.f);
        o6 = fmaxf(c6 * inv + b1.z, 0.f); o7 = fmaxf(c7 * inv + b1.w, 0.f);
    }

    if (!HEAD) {
        if (g == 0) {
            union { unsigned short us[8]; uint4 u4; } pk;
            pk.us[0] = f2bf(o0); pk.us[1] = f2bf(o1);
            pk.us[2] = f2bf(o2); pk.us[3] = f2bf(o3);
            pk.us[4] = f2bf(o4); pk.us[5] = f2bf(o5);
            pk.us[6] = f2bf(o6); pk.us[7] = f2bf(o7);
            *(uint4*)(outC + (size_t)node * FDIM + col) = pk.u4;
        }
        return;
    }
    // ---- fused head: wave-local LDS transpose, 128->16 dot, log_softmax ----
    if (g == 0) {
        *(float4*)&stage[w][col]     = make_float4(o0, o1, o2, o3);
        *(float4*)&stage[w][col + 4] = make_float4(o4, o5, o6, o7);
    }
    const int cls = lane & 15;
    const int q = lane >> 4;          // quarter of the k-range
    float acc = 0.f;
#pragma unroll
    for (int k = 0; k < 32; k++)
        acc += stage[w][q * 32 + k] * WsL[(q * 32 + k) * NCLS + cls];
    acc += __shfl_xor(acc, 16, 64);
    acc += __shfl_xor(acc, 32, 64);
    acc += headB[cls];
    float m2 = acc;
    m2 = fmaxf(m2, __shfl_xor(m2, 8, 64));
    m2 = fmaxf(m2, __shfl_xor(m2, 4, 64));
    m2 = fmaxf(m2, __shfl_xor(m2, 2, 64));
    m2 = fmaxf(m2, __shfl_xor(m2, 1, 64));
    float sm = __expf(acc - m2);
    sm += __shfl_xor(sm, 8, 64);
    sm += __shfl_xor(sm, 4, 64);
    sm += __shfl_xor(sm, 2, 64);
    sm += __shfl_xor(sm, 1, 64);
    if (lane < 16)
        outH[(size_t)node * NCLS + cls] = acc - m2 - __logf(sm);
}

// ==============================================================================
extern "C" void kernel_launch(void* const* d_in, const int* in_sizes, int n_in,
                              void* d_out, int out_size, void* d_ws, size_t ws_size,
                              hipStream_t stream) {
    const float* x    = (const float*)d_in[0];
    const int*   edge = (const int*)d_in[1];
    const float* Wl1  = (const float*)d_in[2];
    const float* Wr1  = (const float*)d_in[3];
    const float* att1 = (const float*)d_in[4];
    const float* b1   = (const float*)d_in[5];
    const float* Wl2  = (const float*)d_in[6];
    const float* Wr2  = (const float*)d_in[7];
    const float* att2 = (const float*)d_in[8];
    const float* b2   = (const float*)d_in[9];
    const float* Wlin = (const float*)d_in[10];
    const float* blin = (const float*)d_in[11];

    const int N = in_sizes[0] / FDIM;        // 50000
    const int E0 = in_sizes[1] / 2;          // 1600000
    const int* srcs = edge;
    const int* dsts = edge + E0;

    // padded adjacency: in-degree is ~Poisson(32); PAD=96 is ~1e-13-safe.
    int PAD = 96;
    {
        size_t need = (size_t)3 * N * FDIM * 2 + (size_t)N * 4 + (size_t)N * PAD * 4
                    + 4 * 16384 * 2;
        if (need > ws_size) PAD = 72;   // still ~1e-9-safe
    }

    unsigned short* A = (unsigned short*)d_ws;      // xl bf16  N*128
    unsigned short* B = A + (size_t)N * FDIM;       // xr bf16  N*128
    unsigned short* C = B + (size_t)N * FDIM;       // conv1 out bf16 N*128
    int* cnt   = (int*)(C + (size_t)N * FDIM);      // N
    int* adj   = cnt + N;                           // N*PAD
    unsigned short* Wsw = (unsigned short*)(adj + (size_t)N * PAD);  // 4*16384

    const int GB = (N + 127) / 128;          // 391: 2 tiles per block per side
    const int G  = 2 * GB;                   // 782 gemm blocks
    const int SB = (G + 3) / 4;              // scatter blocks, 1:4 interleave
    const int node_blocks = (N + 3) / 4;

    // ---- prep: swizzle W matrices (blocks 0-3) + zero cnt (blocks 4+) ----
    prep<<<4 + 64, 256, 0, stream>>>(Wl1, Wr1, Wl2, Wr2, Wsw, cnt, N);

    // ---- layer 1: dual MFMA-GEMM + interleaved CSR scatter (grid = 5*SB) ----
    gemm_csr<<<5 * SB, 256, 0, stream>>>(
        x, nullptr, Wsw, Wsw + 16384, A, B, N, srcs, dsts, cnt, adj, E0, PAD, GB, SB);
    node_gather<false><<<node_blocks, 256, 0, stream>>>(
        A, B, att1, adj, cnt, b1, C, nullptr, nullptr, nullptr, N, PAD);

    // ---- layer 2 (X = bf16 conv1 output) ----
    gemm_csr<<<G, 256, 0, stream>>>(
        nullptr, C, Wsw + 2 * 16384, Wsw + 3 * 16384, A, B, N,
        nullptr, nullptr, nullptr, nullptr, 0, PAD, GB, 0);
    node_gather<true><<<node_blocks, 256, 0, stream>>>(
        A, B, att2, adj, cnt, b2, nullptr, Wlin, blin, (float*)d_out, N, PAD);
}